// Round 1
// baseline (1549.494 us; speedup 1.0000x reference)
//
#include <hip/hip_runtime.h>

#define IN_F 256
#define OUT_F 128
#define NUM_REL 4

typedef unsigned int u32;
typedef unsigned short u16;

// ---------- helpers ----------
static __device__ __forceinline__ u16 f32_to_bf16(float f) {
    union { float f; u32 u; } c; c.f = f;
    u32 u = c.u;
    u32 r = (u + 0x7fffu + ((u >> 16) & 1u)) >> 16;   // RNE
    return (u16)r;
}
static __device__ __forceinline__ float bf16lo(u32 v) {
    union { u32 u; float f; } c; c.u = v << 16; return c.f;
}
static __device__ __forceinline__ float bf16hi(u32 v) {
    union { u32 u; float f; } c; c.u = v & 0xffff0000u; return c.f;
}

// ---------- 1. degree count ----------
__global__ void count_kernel(const int* __restrict__ EI, int* __restrict__ deg_out,
                             int* __restrict__ deg_in, int N, int E, int r0) {
    int rr = blockIdx.y;
    int r = r0 + rr;
    const int* src = EI + (size_t)(2 * r) * E;
    const int* dst = src + E;
    int* dout = deg_out + (size_t)rr * N;
    int* din  = deg_in  + (size_t)rr * N;
    for (int e = blockIdx.x * blockDim.x + threadIdx.x; e < E; e += gridDim.x * blockDim.x) {
        atomicAdd(&dout[src[e]], 1);
        atomicAdd(&din[dst[e]], 1);
    }
}

// ---------- 2. exclusive scan of in-degrees -> CSR offsets (one block per relation) ----------
__global__ __launch_bounds__(1024) void scan_kernel(const int* __restrict__ deg_in,
                                                    int* __restrict__ offsets, int N) {
    int rr = blockIdx.x;
    const int* d = deg_in + (size_t)rr * N;
    int* o = offsets + (size_t)rr * (N + 1);
    __shared__ int s[1024];
    __shared__ int carry_s;
    int t = threadIdx.x;
    if (t == 0) carry_s = 0;
    __syncthreads();
    for (int base = 0; base < N; base += 1024) {
        int i = base + t;
        int v = (i < N) ? d[i] : 0;
        s[t] = v;
        __syncthreads();
        #pragma unroll
        for (int off = 1; off < 1024; off <<= 1) {
            int x = (t >= off) ? s[t - off] : 0;
            __syncthreads();
            s[t] += x;
            __syncthreads();
        }
        int incl = s[t];
        int carry = carry_s;
        if (i < N) o[i] = carry + incl - v;
        __syncthreads();
        if (t == 1023) carry_s = carry + incl;
        __syncthreads();
    }
    if (t == 0) o[N] = carry_s;
}

// ---------- 3. degrees -> norms, in place (int -> float reinterpret) ----------
__global__ void norm_kernel(int* __restrict__ a, int* __restrict__ b, int tot) {
    for (int i = blockIdx.x * blockDim.x + threadIdx.x; i < tot; i += gridDim.x * blockDim.x) {
        int ca = a[i]; if (ca < 1) ca = 1;
        int cb = b[i]; if (cb < 1) cb = 1;
        ((float*)a)[i] = rsqrtf((float)ca);
        ((float*)b)[i] = rsqrtf((float)cb);
    }
}

// ---------- 4. counting-sort fill: sorted_src bucketed by dst ----------
__global__ void fill_kernel(const int* __restrict__ EI, const int* __restrict__ offsets,
                            int* __restrict__ cursor, int* __restrict__ sorted,
                            int N, int E, int r0) {
    int rr = blockIdx.y;
    int r = r0 + rr;
    const int* src = EI + (size_t)(2 * r) * E;
    const int* dst = src + E;
    const int* off = offsets + (size_t)rr * (N + 1);
    int* cur = cursor + (size_t)rr * N;
    int* srt = sorted + (size_t)rr * E;
    for (int e = blockIdx.x * blockDim.x + threadIdx.x; e < E; e += gridDim.x * blockDim.x) {
        int d = dst[e];
        int pos = off[d] + atomicAdd(&cur[d], 1);
        srt[pos] = src[e];
    }
}

// ---------- 5. h[rr] = (out_norm_rr * X) @ W[r0+rr], stored bf16 ----------
#define BM 64
#define BK 32
__global__ __launch_bounds__(256) void gemm_kernel(const float* __restrict__ X,
                                                   const float* __restrict__ W,
                                                   const float* __restrict__ out_normf,
                                                   u16* __restrict__ h, int N, int r0) {
    int rr = blockIdx.y;
    int r = r0 + rr;
    int row0 = blockIdx.x * BM;
    __shared__ float As[BK][BM + 1];
    __shared__ float Bs[BK][OUT_F];
    int t = threadIdx.x;
    int tx = t & 15, ty = t >> 4;
    float acc[4][8] = {};
    const float* Wr = W + (size_t)r * IN_F * OUT_F;
    const float* norm = out_normf + (size_t)rr * N;

    for (int k0 = 0; k0 < IN_F; k0 += BK) {
        // stage A tile (64 rows x 32 cols), scaled by out_norm[row]
        #pragma unroll
        for (int l = 0; l < 2; l++) {
            int j = t + l * 256;          // 0..511
            int m = j >> 3, q = j & 7;    // row-in-tile, float4-in-row
            int row = row0 + m;
            float4 v = make_float4(0.f, 0.f, 0.f, 0.f);
            float nv = 0.f;
            if (row < N) {
                v = *(const float4*)(X + (size_t)row * IN_F + k0 + q * 4);
                nv = norm[row];
            }
            As[q * 4 + 0][m] = v.x * nv;
            As[q * 4 + 1][m] = v.y * nv;
            As[q * 4 + 2][m] = v.z * nv;
            As[q * 4 + 3][m] = v.w * nv;
        }
        // stage B tile (32 x 128)
        #pragma unroll
        for (int l = 0; l < 4; l++) {
            int j = t + l * 256;          // 0..1023
            int k = j >> 5, q = j & 31;
            float4 v = *(const float4*)(Wr + (size_t)(k0 + k) * OUT_F + q * 4);
            *(float4*)&Bs[k][q * 4] = v;
        }
        __syncthreads();
        #pragma unroll
        for (int k = 0; k < BK; k++) {
            float a[4];
            #pragma unroll
            for (int i = 0; i < 4; i++) a[i] = As[k][ty * 4 + i];
            float4 b0 = *(float4*)&Bs[k][tx * 8];
            float4 b1 = *(float4*)&Bs[k][tx * 8 + 4];
            float bb[8] = {b0.x, b0.y, b0.z, b0.w, b1.x, b1.y, b1.z, b1.w};
            #pragma unroll
            for (int i = 0; i < 4; i++)
                #pragma unroll
                for (int jx = 0; jx < 8; jx++)
                    acc[i][jx] += a[i] * bb[jx];
        }
        __syncthreads();
    }
    // store 4 rows x 8 cols as bf16 (16B per row-chunk)
    u16* hr = h + (size_t)rr * N * OUT_F;
    #pragma unroll
    for (int i = 0; i < 4; i++) {
        int row = row0 + ty * 4 + i;
        if (row >= N) continue;
        u16 u[8];
        #pragma unroll
        for (int jx = 0; jx < 8; jx++) u[jx] = f32_to_bf16(acc[i][jx]);
        *(uint4*)(hr + (size_t)row * OUT_F + tx * 8) = *(uint4*)u;
    }
}

// ---------- 6. gather-aggregate: one wave per dst node ----------
__global__ __launch_bounds__(256) void aggregate_kernel(const int* __restrict__ sorted,
                                                        const int* __restrict__ offsets,
                                                        const u16* __restrict__ h,
                                                        const float* __restrict__ in_normf,
                                                        float* __restrict__ Z,
                                                        int N, int E, int nrel) {
    int wid = (blockIdx.x * blockDim.x + threadIdx.x) >> 6;
    int lane = threadIdx.x & 63;
    if (wid >= N) return;
    int dst = wid;
    float t0 = 0.f, t1 = 0.f;
    for (int rr = 0; rr < nrel; rr++) {
        const int* off = offsets + (size_t)rr * (N + 1);
        int b = off[dst], e = off[dst + 1];
        const int* srt = sorted + (size_t)rr * E;
        const u16* hrr = h + (size_t)rr * N * OUT_F;
        float a0 = 0.f, a1 = 0.f;
        if (b < e) {
            int s_next = srt[b];
            for (int i = b; i < e; ) {
                int s = s_next;
                ++i;
                if (i < e) s_next = srt[i];           // prefetch next src
                u32 v = *(const u32*)(hrr + (size_t)s * OUT_F + lane * 2);
                a0 += bf16lo(v);
                a1 += bf16hi(v);
            }
        }
        float inr = in_normf[(size_t)rr * N + dst];
        t0 += inr * a0;
        t1 += inr * a1;
    }
    float2* zp = (float2*)(Z + (size_t)dst * OUT_F + lane * 2);
    float2 z = *zp;
    z.x += t0; z.y += t1;
    *zp = z;
}

// ---------- host ----------
extern "C" void kernel_launch(void* const* d_in, const int* in_sizes, int n_in,
                              void* d_out, int out_size, void* d_ws, size_t ws_size,
                              hipStream_t stream) {
    const float* X = (const float*)d_in[0];
    const float* W = (const float*)d_in[1];
    const int* EI = (const int*)d_in[2];
    float* Z = (float*)d_out;
    const int N = in_sizes[0] / IN_F;
    const int E = in_sizes[2] / (NUM_REL * 2);

    hipMemsetAsync(d_out, 0, (size_t)N * OUT_F * sizeof(float), stream);

    // ws layout
    size_t deg_out_o, deg_in_o, offs_o, cur_o, sort_o, h_o;
    auto layout = [&](int nrel) -> size_t {
        size_t off = 0;
        auto alloc = [&](size_t bytes) {
            size_t o = off; off = (off + bytes + 255) & ~(size_t)255; return o;
        };
        deg_out_o = alloc((size_t)nrel * N * 4);
        deg_in_o  = alloc((size_t)nrel * N * 4);
        offs_o    = alloc((size_t)nrel * (N + 1) * 4);
        cur_o     = alloc((size_t)nrel * N * 4);
        sort_o    = alloc((size_t)nrel * E * 4);
        h_o       = alloc((size_t)nrel * N * OUT_F * 2);
        return off;
    };
    int nb = (layout(NUM_REL) <= ws_size) ? NUM_REL : 1;
    layout(nb);  // recompute offsets for chosen batch size
    char* ws = (char*)d_ws;

    for (int r0 = 0; r0 < NUM_REL; r0 += nb) {
        int* deg_out = (int*)(ws + deg_out_o);
        int* deg_in  = (int*)(ws + deg_in_o);
        int* offs    = (int*)(ws + offs_o);
        int* cursor  = (int*)(ws + cur_o);
        int* sorted  = (int*)(ws + sort_o);
        u16* h       = (u16*)(ws + h_o);

        hipMemsetAsync(deg_out, 0, (size_t)nb * N * 4, stream);
        hipMemsetAsync(deg_in,  0, (size_t)nb * N * 4, stream);
        hipMemsetAsync(cursor,  0, (size_t)nb * N * 4, stream);

        dim3 gE(2048, nb);
        count_kernel<<<gE, 256, 0, stream>>>(EI, deg_out, deg_in, N, E, r0);
        scan_kernel<<<nb, 1024, 0, stream>>>(deg_in, offs, N);
        int tot = nb * N;
        norm_kernel<<<(tot + 255) / 256, 256, 0, stream>>>(deg_out, deg_in, tot);
        fill_kernel<<<gE, 256, 0, stream>>>(EI, offs, cursor, sorted, N, E, r0);
        gemm_kernel<<<dim3((N + BM - 1) / BM, nb), 256, 0, stream>>>(
            X, W, (const float*)deg_out, h, N, r0);
        aggregate_kernel<<<((size_t)N * 64 + 255) / 256, 256, 0, stream>>>(
            sorted, offs, h, (const float*)deg_in, Z, N, E, nb);
    }
}